// Round 8
// baseline (103.885 us; speedup 1.0000x reference)
//
#include <hip/hip_runtime.h>

namespace {
constexpr int kNE = 14;
constexpr int kNC = 20;
constexpr int kCloner = 13;
constexpr int kCA = 17;   // NE + 3
constexpr int kB = 32;
constexpr int kH = 256;
constexpr int kW = 256;

constexpr int kSH = 4;        // stripe height (full width)
constexpr int kThreads = 256;
constexpr size_t kPlane = (size_t)kH * kW;

// fallback tile geometry (round-3 kernel)
constexpr int kT = 32;
constexpr int kE = kT + 4;
constexpr int kLW = 40;
}

// pack (uint8): bits0..3 label (argmax of one-hot 0..13) | bits4..7 ca_init
// CA state (uint16): bit0 empty | bit1 active | bits4..7 fca | bits8..11 src | bit12 overwritten

// ---------------- K1: per-pixel pack, pure streaming (15R, 1 tiny W) ----------------
__global__ __launch_bounds__(kThreads)
void k_pack(const float* __restrict__ world, const float* __restrict__ info,
            float* __restrict__ out, unsigned char* __restrict__ pack)
{
    const int g = blockIdx.x * kThreads + threadIdx.x;   // 524288 float4-groups
    const int b = g >> 14;                                // 16384 groups per plane
    const int rem = g & 16383;
    const size_t off = (size_t)rem << 2;
    const float* wb = world + (size_t)b * kNC * kPlane;

    int lab[4] = {0, 0, 0, 0};
    #pragma unroll
    for (int c = 0; c < kNE; ++c) {
        const float4 v = *reinterpret_cast<const float4*>(wb + (size_t)c * kPlane + off);
        if (v.x > 0.5f) lab[0] = c;      // exact one-hot: unique channel holds 1.0
        if (v.y > 0.5f) lab[1] = c;
        if (v.z > 0.5f) lab[2] = c;
        if (v.w > 0.5f) lab[3] = c;
    }
    const float4 ca4 = *reinterpret_cast<const float4*>(wb + (size_t)kCA * kPlane + off);
    uchar4 p;
    p.x = (unsigned char)(lab[0] | ((int)ca4.x << 4));
    p.y = (unsigned char)(lab[1] | ((int)ca4.y << 4));
    p.z = (unsigned char)(lab[2] | ((int)ca4.z << 4));
    p.w = (unsigned char)(lab[3] | ((int)ca4.w << 4));
    *reinterpret_cast<uchar4*>(pack + (size_t)b * kPlane + off) = p;

    if (g < kB) out[(size_t)kB * kNC * kPlane + g] = info[g];   // info passthrough
}

// one mask-evolution step: self s, neighbor ns (both CA-state words)
__device__ __forceinline__ unsigned bc_step(unsigned s, unsigned ns,
                                            const unsigned short* __restrict__ vb) {
    if ((ns & 2u) && (s & 1u)) {
        const unsigned v = (ns >> 4) & 15u;
        return (s & 0x00F0u) | vb[v] | (v << 8) | 0x1000u;
    }
    return s;
}

// ---------------- K2<MODE>: stripe CA evolution + channel-subset write --------------
// MODE 0 ("expand"):      writes ch 0..13 + 17 (pack-derived); reads only pack.
// MODE 1 ("passthrough"): reads+writes ch 14,15,16,18,19.
// Overwritten pixels (~1.7%) are patched with exec-masked scalar stores AFTER the
// dense base store (same thread, same wave -> ordered, line merges in L2).
template <int MODE>
__global__ __launch_bounds__(kThreads)
void k_apply(const float* __restrict__ world, const float* __restrict__ ev,
             const unsigned char* __restrict__ pack, float* __restrict__ out)
{
    __shared__ unsigned char  sP[kSH + 4][kW];   // rows y0-2 .. y0+5 (wrapped)
    __shared__ unsigned short sA[kSH + 2][kW];   // CA state rows y0-1 .. y0+4
    __shared__ float sEV[kNE * kNC];
    __shared__ unsigned short sVbits[kNE];

    const int tid = threadIdx.x;
    const int y0 = blockIdx.x * kSH;
    const int b  = blockIdx.y;
    const float* wb = world + (size_t)b * kNC * kPlane;
    float*       ob = out   + (size_t)b * kNC * kPlane;
    const unsigned char* pb = pack + (size_t)b * kPlane;

    const int th   = tid >> 6;              // row in stripe (0..3); wave = 1 full row
    const int col4 = (tid & 63) * 4;
    const size_t off4 = (size_t)(y0 + th) * kW + col4;

    float4 extra[5];
    if (MODE == 1) {   // early-issue passthrough loads; latency hides under LDS phases
        extra[0] = *reinterpret_cast<const float4*>(wb + (size_t)14 * kPlane + off4);
        extra[1] = *reinterpret_cast<const float4*>(wb + (size_t)15 * kPlane + off4);
        extra[2] = *reinterpret_cast<const float4*>(wb + (size_t)16 * kPlane + off4);
        extra[3] = *reinterpret_cast<const float4*>(wb + (size_t)18 * kPlane + off4);
        extra[4] = *reinterpret_cast<const float4*>(wb + (size_t)19 * kPlane + off4);
    }

    for (int i = tid; i < kNE * kNC; i += kThreads) sEV[i] = ev[i];
    if (tid < kNE) {
        const float e0  = ev[tid * kNC + 0];
        const float c13 = ev[tid * kNC + kCloner];
        const float c17 = ev[tid * kNC + kCA];
        unsigned short vb = 0;
        if (e0 > 0.5f) vb |= 1;                                     // empty after overwrite
        if (c13 > 0.5f && c17 != 0.0f && c17 != 13.0f) vb |= 2;     // active after overwrite
        sVbits[tid] = vb;
    }

    // pack rows y0-2..y0+5 (uchar4, contiguous per row; row wrap via &255)
    for (int idx = tid; idx < (kSH + 4) * (kW / 4); idx += kThreads) {
        const int r  = idx >> 6;            // 0..7
        const int c4 = (idx & 63) * 4;
        const int h  = (y0 - 2 + r) & (kH - 1);
        *reinterpret_cast<uchar4*>(&sP[r][c4]) =
            *reinterpret_cast<const uchar4*>(pb + (size_t)h * kW + c4);
    }
    __syncthreads();

    // phase A: final CA + state init on rows y0-1..y0+4 (sP rows 1..6), full width
    for (int idx = tid; idx < (kSH + 2) * kW; idx += kThreads) {
        const int r   = idx >> 8;           // 0..5 (sA row)
        const int col = idx & 255;
        const int pr  = r + 1;              // sP row
        const unsigned p  = sP[pr][col];
        const unsigned lb = p & 15u;
        int fca = 0;
        if (lb == kCloner) {                // cloner: sequentially absorb neighbor labels
            int ca = (int)(p >> 4);
            if (ca == 0 || ca == 13) ca = sP[pr + 1][col] & 15;            // below
            if (ca == 0 || ca == 13) ca = sP[pr - 1][col] & 15;            // above
            if (ca == 0 || ca == 13) ca = sP[pr][(col - 1) & 255] & 15;    // left
            if (ca == 0 || ca == 13) ca = sP[pr][(col + 1) & 255] & 15;    // right
            fca = ca;
        }
        unsigned short s = (unsigned short)(fca << 4);
        if (lb == 0) s |= 1;                                  // empty
        if (lb == kCloner && fca != 0 && fca != 13) s |= 2;   // active
        sA[r][col] = s;
    }
    __syncthreads();

    // phase B in registers: 4 direction steps over the 3x6 cone (column-wrapped)
    const int ar = th + 1;                  // sA row of the output row
    unsigned s0[3][6];
    #pragma unroll
    for (int r = 0; r < 3; ++r)
        #pragma unroll
        for (int c = 0; c < 6; ++c)
            s0[r][c] = sA[ar - 1 + r][(col4 - 1 + c) & 255];

    unsigned s1[2][6];
    #pragma unroll
    for (int r = 0; r < 2; ++r)
        #pragma unroll
        for (int c = 0; c < 6; ++c)
            s1[r][c] = bc_step(s0[r][c], s0[r + 1][c], sVbits);   // below

    unsigned s2[6];
    #pragma unroll
    for (int c = 0; c < 6; ++c)
        s2[c] = bc_step(s1[1][c], s1[0][c], sVbits);              // above

    unsigned s3[5];
    #pragma unroll
    for (int c = 0; c < 5; ++c)
        s3[c] = bc_step(s2[c + 1], s2[c], sVbits);                // left

    unsigned s4[4];
    #pragma unroll
    for (int j = 0; j < 4; ++j)
        s4[j] = bc_step(s3[j], s3[j + 1], sVbits);                // right

    if (MODE == 0) {
        int lb[4]; float fcaf[4];
        #pragma unroll
        for (int j = 0; j < 4; ++j) {
            lb[j]   = sP[th + 2][col4 + j] & 15;
            fcaf[j] = (float)((s4[j] >> 4) & 15);
        }
        // dense base stores: one-hot channels + ch17 (no sEV access)
        #pragma unroll
        for (int c = 0; c < kNE; ++c) {
            float4 r;
            r.x = (lb[0] == c) ? 1.0f : 0.0f;
            r.y = (lb[1] == c) ? 1.0f : 0.0f;
            r.z = (lb[2] == c) ? 1.0f : 0.0f;
            r.w = (lb[3] == c) ? 1.0f : 0.0f;
            *reinterpret_cast<float4*>(ob + (size_t)c * kPlane + off4) = r;
        }
        {
            float4 r; r.x = fcaf[0]; r.y = fcaf[1]; r.z = fcaf[2]; r.w = fcaf[3];
            *reinterpret_cast<float4*>(ob + (size_t)kCA * kPlane + off4) = r;
        }
        // sparse patches: exec-masked scalar stores, LDS reads only on active lanes
        #pragma unroll
        for (int j = 0; j < 4; ++j) {
            if (s4[j] & 0x1000u) {
                const float* vv = &sEV[((s4[j] >> 8) & 15) * kNC];
                float* op = ob + off4 + j;
                #pragma unroll
                for (int c = 0; c < kNE; ++c) op[(size_t)c * kPlane] = vv[c];
                op[(size_t)kCA * kPlane] = vv[kCA];
            }
        }
    } else {
        const int chans[5] = {14, 15, 16, 18, 19};
        #pragma unroll
        for (int k = 0; k < 5; ++k) {
            *reinterpret_cast<float4*>(ob + (size_t)chans[k] * kPlane + off4) = extra[k];
        }
        #pragma unroll
        for (int j = 0; j < 4; ++j) {
            if (s4[j] & 0x1000u) {
                const float* vv = &sEV[((s4[j] >> 8) & 15) * kNC];
                float* op = ob + off4 + j;
                #pragma unroll
                for (int k = 0; k < 5; ++k) op[(size_t)chans[k] * kPlane] = vv[chans[k]];
            }
        }
    }
}

// ---------------- Fallback (round-3 fused kernel), used only if ws too small ----------
__global__ __launch_bounds__(kThreads)
void bc_fused(const float* __restrict__ world, const float* __restrict__ ev,
              const float* __restrict__ info, float* __restrict__ out)
{
    __shared__ unsigned short sPack[kE][kLW];
    __shared__ unsigned short sA[kE][kLW];
    __shared__ unsigned short sB[kE][kLW];
    __shared__ float sEV[kNE * kNC];
    __shared__ unsigned short sVbits[kNE];

    const int tid = threadIdx.x;
    const int b  = blockIdx.z;
    const int h0 = blockIdx.y * kT;
    const int w0 = blockIdx.x * kT;
    const float* wb = world + (size_t)b * kNC * kPlane;
    float*       ob = out   + (size_t)b * kNC * kPlane;

    for (int i = tid; i < kNE * kNC; i += kThreads) sEV[i] = ev[i];
    if (tid < kNE) {
        const float e0  = ev[tid * kNC + 0];
        const float c13 = ev[tid * kNC + kCloner];
        const float c17 = ev[tid * kNC + kCA];
        unsigned short vb = 0;
        if (e0 > 0.5f) vb |= 1;
        if (c13 > 0.5f && c17 != 0.0f && c17 != 13.0f) vb |= 2;
        sVbits[tid] = vb;
    }
    for (int idx = tid; idx < kE * 10; idx += kThreads) {
        const int eh = idx / 10;
        const int k  = idx - eh * 10;
        const int h = (h0 + eh - 2) & (kH - 1);
        const int w = (w0 - 4 + 4 * k) & (kW - 1);
        const size_t off = (size_t)h * kW + w;
        int lab[4] = {0,0,0,0};
        #pragma unroll
        for (int c = 0; c < kNE; ++c) {
            const float4 v = *reinterpret_cast<const float4*>(wb + (size_t)c * kPlane + off);
            if (v.x > 0.5f) lab[0] = c;
            if (v.y > 0.5f) lab[1] = c;
            if (v.z > 0.5f) lab[2] = c;
            if (v.w > 0.5f) lab[3] = c;
        }
        const float4 ca4 = *reinterpret_cast<const float4*>(wb + (size_t)kCA * kPlane + off);
        const int cai[4] = {(int)ca4.x, (int)ca4.y, (int)ca4.z, (int)ca4.w};
        #pragma unroll
        for (int j = 0; j < 4; ++j) {
            unsigned short p = (unsigned short)(lab[j] | (cai[j] << 8));
            if (lab[j] == kCloner) p |= 16;
            if (lab[j] == 0)       p |= 32;
            sPack[eh][4 * k + j] = p;
        }
    }
    __syncthreads();
    for (int idx = tid; idx < 34 * 34; idx += kThreads) {
        const int eh = idx / 34 + 1;
        const int lw = idx % 34 + 3;
        const unsigned short p = sPack[eh][lw];
        int fca = 0;
        if (p & 16) {
            int ca = (p >> 8) & 15;
            if (ca == 0 || ca == 13) ca = sPack[eh + 1][lw] & 15;
            if (ca == 0 || ca == 13) ca = sPack[eh - 1][lw] & 15;
            if (ca == 0 || ca == 13) ca = sPack[eh][lw - 1] & 15;
            if (ca == 0 || ca == 13) ca = sPack[eh][lw + 1] & 15;
            fca = ca;
        }
        unsigned short s = (unsigned short)(fca << 4);
        if (p & 32) s |= 1;
        if ((p & 16) && fca != 0 && fca != 13) s |= 2;
        sA[eh][lw] = s;
    }
    unsigned short (*prev)[kLW] = sA;
    unsigned short (*next)[kLW] = sB;
    {
        const int dh[4]   = {1, -1, 0, 0};
        const int dw[4]   = {0, 0, -1, 1};
        const int rhlo[4] = {1, 2, 2, 2};
        const int rhhi[4] = {33, 33, 33, 33};
        const int rwlo[4] = {3, 3, 4, 4};
        const int rwhi[4] = {36, 36, 36, 35};
        for (int d = 0; d < 4; ++d) {
            __syncthreads();
            const int nh = rhhi[d] - rhlo[d] + 1;
            const int nw = rwhi[d] - rwlo[d] + 1;
            for (int idx = tid; idx < nh * nw; idx += kThreads) {
                const int eh = rhlo[d] + idx / nw;
                const int lw = rwlo[d] + idx % nw;
                unsigned short s = prev[eh][lw];
                const unsigned short ns = prev[eh + dh[d]][lw + dw[d]];
                if ((ns & 2) && (s & 1)) {
                    const int v = (ns >> 4) & 15;
                    s = (unsigned short)((s & 0x00F0) | sVbits[v] | (v << 8) | 0x1000);
                }
                next[eh][lw] = s;
            }
            unsigned short (*t)[kLW] = prev; prev = next; next = t;
        }
    }
    __syncthreads();
    {
        const int th = tid >> 3;
        const int tw = (tid & 7) * 4;
        const int eh = th + 2;
        const size_t off = (size_t)(h0 + th) * kW + (w0 + tw);
        bool  o[4]; int src[4]; float fcaf[4]; int lb[4];
        #pragma unroll
        for (int j = 0; j < 4; ++j) {
            const unsigned short s = prev[eh][tw + 4 + j];
            o[j]    = (s & 0x1000) != 0;
            src[j]  = (s >> 8) & 15;
            fcaf[j] = (float)((s >> 4) & 15);
            lb[j]   = sPack[eh][tw + 4 + j] & 15;
        }
        #pragma unroll
        for (int c = 0; c < kNC; ++c) {
            float base[4];
            if (c >= kNE && c != kCA) {
                const float4 v = *reinterpret_cast<const float4*>(wb + (size_t)c * kPlane + off);
                base[0] = v.x; base[1] = v.y; base[2] = v.z; base[3] = v.w;
            } else if (c == kCA) {
                base[0] = fcaf[0]; base[1] = fcaf[1]; base[2] = fcaf[2]; base[3] = fcaf[3];
            } else {
                #pragma unroll
                for (int j = 0; j < 4; ++j) base[j] = (lb[j] == c) ? 1.0f : 0.0f;
            }
            float4 r;
            r.x = o[0] ? sEV[src[0] * kNC + c] : base[0];
            r.y = o[1] ? sEV[src[1] * kNC + c] : base[1];
            r.z = o[2] ? sEV[src[2] * kNC + c] : base[2];
            r.w = o[3] ? sEV[src[3] * kNC + c] : base[3];
            *reinterpret_cast<float4*>(ob + (size_t)c * kPlane + off) = r;
        }
    }
    if (blockIdx.x == 0 && blockIdx.y == 0 && blockIdx.z == 0 && tid < kB) {
        out[(size_t)kB * kNC * kPlane + tid] = info[tid];
    }
}

extern "C" void kernel_launch(void* const* d_in, const int* in_sizes, int n_in,
                              void* d_out, int out_size, void* d_ws, size_t ws_size,
                              hipStream_t stream) {
    const float* world = (const float*)d_in[0];
    const float* ev    = (const float*)d_in[1];
    const float* info  = (const float*)d_in[2];
    float* out = (float*)d_out;
    const size_t packBytes = (size_t)kB * kPlane;   // 2.1 MB (uint8)
    if (ws_size >= packBytes) {
        unsigned char* pack = (unsigned char*)d_ws;
        k_pack<<<dim3((kB * (int)kPlane / 4) / kThreads), kThreads, 0, stream>>>(world, info, out, pack);
        k_apply<0><<<dim3(kH / kSH, kB), kThreads, 0, stream>>>(world, ev, pack, out);
        k_apply<1><<<dim3(kH / kSH, kB), kThreads, 0, stream>>>(world, ev, pack, out);
    } else {
        bc_fused<<<dim3(kW / kT, kH / kT, kB), kThreads, 0, stream>>>(world, ev, info, out);
    }
}

// Round 9
// 103.155 us; speedup vs baseline: 1.0071x; 1.0071x over previous
//
#include <hip/hip_runtime.h>

namespace {
constexpr int kNE = 14;
constexpr int kNC = 20;
constexpr int kCloner = 13;
constexpr int kCA = 17;   // NE + 3
constexpr int kB = 32;
constexpr int kH = 256;
constexpr int kW = 256;

constexpr int kSH = 4;        // stripe height (full width)
constexpr int kThreads = 256;
constexpr size_t kPlane = (size_t)kH * kW;

// fallback tile geometry (round-3 kernel)
constexpr int kT = 32;
constexpr int kE = kT + 4;
constexpr int kLW = 40;
}

// pack  (uint8):  bits0..3 label | bits4..7 ca_init
// sim   (uint16): bit0 empty | bit1 active | bits4..7 fca | bits8..11 src | bit12 ovr
// state (uint16): bits0..3 label | bits4..7 fca | bits8..11 src | bit12 ovr

// ---------------- K1: per-pixel pack, pure streaming (15R, 1 tiny W) ----------------
__global__ __launch_bounds__(kThreads)
void k_pack(const float* __restrict__ world, const float* __restrict__ info,
            float* __restrict__ out, unsigned char* __restrict__ pack)
{
    const int g = blockIdx.x * kThreads + threadIdx.x;   // 524288 float4-groups
    const int b = g >> 14;                                // 16384 groups per plane
    const int rem = g & 16383;
    const size_t off = (size_t)rem << 2;
    const float* wb = world + (size_t)b * kNC * kPlane;

    int lab[4] = {0, 0, 0, 0};
    #pragma unroll
    for (int c = 0; c < kNE; ++c) {
        const float4 v = *reinterpret_cast<const float4*>(wb + (size_t)c * kPlane + off);
        if (v.x > 0.5f) lab[0] = c;      // exact one-hot: unique channel holds 1.0
        if (v.y > 0.5f) lab[1] = c;
        if (v.z > 0.5f) lab[2] = c;
        if (v.w > 0.5f) lab[3] = c;
    }
    const float4 ca4 = *reinterpret_cast<const float4*>(wb + (size_t)kCA * kPlane + off);
    uchar4 p;
    p.x = (unsigned char)(lab[0] | ((int)ca4.x << 4));
    p.y = (unsigned char)(lab[1] | ((int)ca4.y << 4));
    p.z = (unsigned char)(lab[2] | ((int)ca4.z << 4));
    p.w = (unsigned char)(lab[3] | ((int)ca4.w << 4));
    *reinterpret_cast<uchar4*>(pack + (size_t)b * kPlane + off) = p;

    if (g < kB) out[(size_t)kB * kNC * kPlane + g] = info[g];   // info passthrough
}

// one mask-evolution step: self s, neighbor ns (both sim words)
__device__ __forceinline__ unsigned bc_step(unsigned s, unsigned ns,
                                            const unsigned short* __restrict__ vb) {
    if ((ns & 2u) && (s & 1u)) {
        const unsigned v = (ns >> 4) & 15u;
        return (s & 0x00F0u) | vb[v] | (v << 8) | 0x1000u;
    }
    return s;
}

// ---------------- K2: stripe CA sim -> per-pixel final state (2B) ----------------
__global__ __launch_bounds__(kThreads)
void k_state(const float* __restrict__ ev, const unsigned char* __restrict__ pack,
             unsigned short* __restrict__ state)
{
    __shared__ unsigned char  sP[kSH + 4][kW];   // rows y0-2 .. y0+5 (wrapped)
    __shared__ unsigned short sA[kSH + 2][kW];   // sim rows y0-1 .. y0+4
    __shared__ unsigned short sVbits[kNE];

    const int tid = threadIdx.x;
    const int y0 = blockIdx.x * kSH;
    const int b  = blockIdx.y;
    const unsigned char* pb = pack + (size_t)b * kPlane;

    const int th   = tid >> 6;              // row in stripe (0..3); wave = 1 full row
    const int col4 = (tid & 63) * 4;
    const size_t off4 = (size_t)(y0 + th) * kW + col4;

    if (tid < kNE) {
        const float e0  = ev[tid * kNC + 0];
        const float c13 = ev[tid * kNC + kCloner];
        const float c17 = ev[tid * kNC + kCA];
        unsigned short vb = 0;
        if (e0 > 0.5f) vb |= 1;                                     // empty after overwrite
        if (c13 > 0.5f && c17 != 0.0f && c17 != 13.0f) vb |= 2;     // active after overwrite
        sVbits[tid] = vb;
    }

    // pack rows y0-2..y0+5 (uchar4, contiguous per row; row wrap via &255)
    for (int idx = tid; idx < (kSH + 4) * (kW / 4); idx += kThreads) {
        const int r  = idx >> 6;            // 0..7
        const int c4 = (idx & 63) * 4;
        const int h  = (y0 - 2 + r) & (kH - 1);
        *reinterpret_cast<uchar4*>(&sP[r][c4]) =
            *reinterpret_cast<const uchar4*>(pb + (size_t)h * kW + c4);
    }
    __syncthreads();

    // phase A: final CA + sim init on rows y0-1..y0+4 (sP rows 1..6), full width
    for (int idx = tid; idx < (kSH + 2) * kW; idx += kThreads) {
        const int r   = idx >> 8;           // 0..5 (sA row)
        const int col = idx & 255;
        const int pr  = r + 1;              // sP row
        const unsigned p  = sP[pr][col];
        const unsigned lb = p & 15u;
        int fca = 0;
        if (lb == kCloner) {                // cloner: sequentially absorb neighbor labels
            int ca = (int)(p >> 4);
            if (ca == 0 || ca == 13) ca = sP[pr + 1][col] & 15;            // below
            if (ca == 0 || ca == 13) ca = sP[pr - 1][col] & 15;            // above
            if (ca == 0 || ca == 13) ca = sP[pr][(col - 1) & 255] & 15;    // left
            if (ca == 0 || ca == 13) ca = sP[pr][(col + 1) & 255] & 15;    // right
            fca = ca;
        }
        unsigned short s = (unsigned short)(fca << 4);
        if (lb == 0) s |= 1;                                  // empty
        if (lb == kCloner && fca != 0 && fca != 13) s |= 2;   // active
        sA[r][col] = s;
    }
    __syncthreads();

    // phase B in registers: 4 direction steps over the 3x6 cone (column-wrapped)
    const int ar = th + 1;                  // sA row of the output row
    unsigned s0[3][6];
    #pragma unroll
    for (int r = 0; r < 3; ++r)
        #pragma unroll
        for (int c = 0; c < 6; ++c)
            s0[r][c] = sA[ar - 1 + r][(col4 - 1 + c) & 255];

    unsigned s1[2][6];
    #pragma unroll
    for (int r = 0; r < 2; ++r)
        #pragma unroll
        for (int c = 0; c < 6; ++c)
            s1[r][c] = bc_step(s0[r][c], s0[r + 1][c], sVbits);   // below

    unsigned s2[6];
    #pragma unroll
    for (int c = 0; c < 6; ++c)
        s2[c] = bc_step(s1[1][c], s1[0][c], sVbits);              // above

    unsigned s3[5];
    #pragma unroll
    for (int c = 0; c < 5; ++c)
        s3[c] = bc_step(s2[c + 1], s2[c], sVbits);                // left

    unsigned s4[4];
    #pragma unroll
    for (int j = 0; j < 4; ++j)
        s4[j] = bc_step(s3[j], s3[j + 1], sVbits);                // right

    ushort4 st;
    st.x = (unsigned short)((s4[0] & 0x1FF0u) | (sP[th + 2][col4 + 0] & 15u));
    st.y = (unsigned short)((s4[1] & 0x1FF0u) | (sP[th + 2][col4 + 1] & 15u));
    st.z = (unsigned short)((s4[2] & 0x1FF0u) | (sP[th + 2][col4 + 2] & 15u));
    st.w = (unsigned short)((s4[3] & 0x1FF0u) | (sP[th + 2][col4 + 3] & 15u));
    *reinterpret_cast<ushort4*>(state + (size_t)b * kPlane + off4) = st;
}

// ---------------- K3: expand state -> one contiguous quarter-plane per block ----------
// bid = xcd + 8*(q + 4*(c + 20*bhi)); b = xcd + 8*bhi  -> same-b blocks share an XCD,
// so the 64KB state quarter is L2-resident after its first reader.
__global__ __launch_bounds__(kThreads)
void k_expand(const float* __restrict__ world, const float* __restrict__ ev,
              const unsigned short* __restrict__ state, float* __restrict__ out)
{
    __shared__ float sEV[kNE * kNC];

    const int bid   = blockIdx.x;
    const int xcd   = bid & 7;
    const int inner = bid >> 3;         // 0..319
    const int q     = inner & 3;
    const int t2    = inner >> 2;       // 0..79
    const int c     = t2 % kNC;
    const int bhi   = t2 / kNC;         // 0..3
    const int b     = xcd + 8 * bhi;

    const int tid = threadIdx.x;
    for (int i = tid; i < kNE * kNC; i += kThreads) sEV[i] = ev[i];
    __syncthreads();

    const unsigned short* sb = state + (size_t)b * kPlane;
    const float* wp = world + ((size_t)b * kNC + c) * kPlane;
    float*       op = out   + ((size_t)b * kNC + c) * kPlane;

    // quarter-plane = 4096 float4-groups; 16 coalesced passes of 256 threads
    #pragma unroll 4
    for (int k = 0; k < 16; ++k) {
        const size_t off = (size_t)(q * 4096 + (k << 8) + tid) << 2;
        const ushort4 st = *reinterpret_cast<const ushort4*>(sb + off);
        const unsigned s[4] = {st.x, st.y, st.z, st.w};
        float4 r;
        float* rp = &r.x;
        if (c < kNE) {
            #pragma unroll
            for (int j = 0; j < 4; ++j)
                rp[j] = (s[j] & 0x1000u) ? sEV[((s[j] >> 8) & 15) * kNC + c]
                                         : (((s[j] & 15u) == (unsigned)c) ? 1.0f : 0.0f);
        } else if (c == kCA) {
            #pragma unroll
            for (int j = 0; j < 4; ++j)
                rp[j] = (s[j] & 0x1000u) ? sEV[((s[j] >> 8) & 15) * kNC + c]
                                         : (float)((s[j] >> 4) & 15);
        } else {
            const float4 in = *reinterpret_cast<const float4*>(wp + off);
            const float* ip = &in.x;
            #pragma unroll
            for (int j = 0; j < 4; ++j)
                rp[j] = (s[j] & 0x1000u) ? sEV[((s[j] >> 8) & 15) * kNC + c] : ip[j];
        }
        *reinterpret_cast<float4*>(op + off) = r;
    }
}

// ---------------- Fallback (round-3 fused kernel), used only if ws too small ----------
__global__ __launch_bounds__(kThreads)
void bc_fused(const float* __restrict__ world, const float* __restrict__ ev,
              const float* __restrict__ info, float* __restrict__ out)
{
    __shared__ unsigned short sPack[kE][kLW];
    __shared__ unsigned short sA[kE][kLW];
    __shared__ unsigned short sB[kE][kLW];
    __shared__ float sEV[kNE * kNC];
    __shared__ unsigned short sVbits[kNE];

    const int tid = threadIdx.x;
    const int b  = blockIdx.z;
    const int h0 = blockIdx.y * kT;
    const int w0 = blockIdx.x * kT;
    const float* wb = world + (size_t)b * kNC * kPlane;
    float*       ob = out   + (size_t)b * kNC * kPlane;

    for (int i = tid; i < kNE * kNC; i += kThreads) sEV[i] = ev[i];
    if (tid < kNE) {
        const float e0  = ev[tid * kNC + 0];
        const float c13 = ev[tid * kNC + kCloner];
        const float c17 = ev[tid * kNC + kCA];
        unsigned short vb = 0;
        if (e0 > 0.5f) vb |= 1;
        if (c13 > 0.5f && c17 != 0.0f && c17 != 13.0f) vb |= 2;
        sVbits[tid] = vb;
    }
    for (int idx = tid; idx < kE * 10; idx += kThreads) {
        const int eh = idx / 10;
        const int k  = idx - eh * 10;
        const int h = (h0 + eh - 2) & (kH - 1);
        const int w = (w0 - 4 + 4 * k) & (kW - 1);
        const size_t off = (size_t)h * kW + w;
        int lab[4] = {0,0,0,0};
        #pragma unroll
        for (int c = 0; c < kNE; ++c) {
            const float4 v = *reinterpret_cast<const float4*>(wb + (size_t)c * kPlane + off);
            if (v.x > 0.5f) lab[0] = c;
            if (v.y > 0.5f) lab[1] = c;
            if (v.z > 0.5f) lab[2] = c;
            if (v.w > 0.5f) lab[3] = c;
        }
        const float4 ca4 = *reinterpret_cast<const float4*>(wb + (size_t)kCA * kPlane + off);
        const int cai[4] = {(int)ca4.x, (int)ca4.y, (int)ca4.z, (int)ca4.w};
        #pragma unroll
        for (int j = 0; j < 4; ++j) {
            unsigned short p = (unsigned short)(lab[j] | (cai[j] << 8));
            if (lab[j] == kCloner) p |= 16;
            if (lab[j] == 0)       p |= 32;
            sPack[eh][4 * k + j] = p;
        }
    }
    __syncthreads();
    for (int idx = tid; idx < 34 * 34; idx += kThreads) {
        const int eh = idx / 34 + 1;
        const int lw = idx % 34 + 3;
        const unsigned short p = sPack[eh][lw];
        int fca = 0;
        if (p & 16) {
            int ca = (p >> 8) & 15;
            if (ca == 0 || ca == 13) ca = sPack[eh + 1][lw] & 15;
            if (ca == 0 || ca == 13) ca = sPack[eh - 1][lw] & 15;
            if (ca == 0 || ca == 13) ca = sPack[eh][lw - 1] & 15;
            if (ca == 0 || ca == 13) ca = sPack[eh][lw + 1] & 15;
            fca = ca;
        }
        unsigned short s = (unsigned short)(fca << 4);
        if (p & 32) s |= 1;
        if ((p & 16) && fca != 0 && fca != 13) s |= 2;
        sA[eh][lw] = s;
    }
    unsigned short (*prev)[kLW] = sA;
    unsigned short (*next)[kLW] = sB;
    {
        const int dh[4]   = {1, -1, 0, 0};
        const int dw[4]   = {0, 0, -1, 1};
        const int rhlo[4] = {1, 2, 2, 2};
        const int rhhi[4] = {33, 33, 33, 33};
        const int rwlo[4] = {3, 3, 4, 4};
        const int rwhi[4] = {36, 36, 36, 35};
        for (int d = 0; d < 4; ++d) {
            __syncthreads();
            const int nh = rhhi[d] - rhlo[d] + 1;
            const int nw = rwhi[d] - rwlo[d] + 1;
            for (int idx = tid; idx < nh * nw; idx += kThreads) {
                const int eh = rhlo[d] + idx / nw;
                const int lw = rwlo[d] + idx % nw;
                unsigned short s = prev[eh][lw];
                const unsigned short ns = prev[eh + dh[d]][lw + dw[d]];
                if ((ns & 2) && (s & 1)) {
                    const int v = (ns >> 4) & 15;
                    s = (unsigned short)((s & 0x00F0) | sVbits[v] | (v << 8) | 0x1000);
                }
                next[eh][lw] = s;
            }
            unsigned short (*t)[kLW] = prev; prev = next; next = t;
        }
    }
    __syncthreads();
    {
        const int th = tid >> 3;
        const int tw = (tid & 7) * 4;
        const int eh = th + 2;
        const size_t off = (size_t)(h0 + th) * kW + (w0 + tw);
        bool  o[4]; int src[4]; float fcaf[4]; int lb[4];
        #pragma unroll
        for (int j = 0; j < 4; ++j) {
            const unsigned short s = prev[eh][tw + 4 + j];
            o[j]    = (s & 0x1000) != 0;
            src[j]  = (s >> 8) & 15;
            fcaf[j] = (float)((s >> 4) & 15);
            lb[j]   = sPack[eh][tw + 4 + j] & 15;
        }
        #pragma unroll
        for (int c = 0; c < kNC; ++c) {
            float base[4];
            if (c >= kNE && c != kCA) {
                const float4 v = *reinterpret_cast<const float4*>(wb + (size_t)c * kPlane + off);
                base[0] = v.x; base[1] = v.y; base[2] = v.z; base[3] = v.w;
            } else if (c == kCA) {
                base[0] = fcaf[0]; base[1] = fcaf[1]; base[2] = fcaf[2]; base[3] = fcaf[3];
            } else {
                #pragma unroll
                for (int j = 0; j < 4; ++j) base[j] = (lb[j] == c) ? 1.0f : 0.0f;
            }
            float4 r;
            r.x = o[0] ? sEV[src[0] * kNC + c] : base[0];
            r.y = o[1] ? sEV[src[1] * kNC + c] : base[1];
            r.z = o[2] ? sEV[src[2] * kNC + c] : base[2];
            r.w = o[3] ? sEV[src[3] * kNC + c] : base[3];
            *reinterpret_cast<float4*>(ob + (size_t)c * kPlane + off) = r;
        }
    }
    if (blockIdx.x == 0 && blockIdx.y == 0 && blockIdx.z == 0 && tid < kB) {
        out[(size_t)kB * kNC * kPlane + tid] = info[tid];
    }
}

extern "C" void kernel_launch(void* const* d_in, const int* in_sizes, int n_in,
                              void* d_out, int out_size, void* d_ws, size_t ws_size,
                              hipStream_t stream) {
    const float* world = (const float*)d_in[0];
    const float* ev    = (const float*)d_in[1];
    const float* info  = (const float*)d_in[2];
    float* out = (float*)d_out;
    const size_t packBytes  = (size_t)kB * kPlane;                         // 2.1 MB
    const size_t stateBytes = (size_t)kB * kPlane * sizeof(unsigned short); // 4.2 MB
    if (ws_size >= packBytes + stateBytes) {
        unsigned char*  pack  = (unsigned char*)d_ws;
        unsigned short* state = (unsigned short*)((char*)d_ws + packBytes);
        k_pack<<<dim3((kB * (int)kPlane / 4) / kThreads), kThreads, 0, stream>>>(world, info, out, pack);
        k_state<<<dim3(kH / kSH, kB), kThreads, 0, stream>>>(ev, pack, state);
        k_expand<<<dim3(kB * kNC * 4), kThreads, 0, stream>>>(world, ev, state, out);
    } else {
        bc_fused<<<dim3(kW / kT, kH / kT, kB), kThreads, 0, stream>>>(world, ev, info, out);
    }
}

// Round 11
// 64.996 us; speedup vs baseline: 1.5983x; 1.5871x over previous
//
#include <hip/hip_runtime.h>

namespace {
constexpr int kNE = 14;
constexpr int kNC = 20;
constexpr int kCloner = 13;
constexpr int kCA = 17;   // NE + 3
constexpr int kB = 32;
constexpr int kH = 256;
constexpr int kW = 256;

constexpr int kSH = 4;        // stripe height (full width)
constexpr int kThreads = 256;
constexpr size_t kPlane = (size_t)kH * kW;

// fallback tile geometry (round-3 kernel)
constexpr int kT = 32;
constexpr int kE = kT + 4;
constexpr int kLW = 40;
}

typedef float floatx4 __attribute__((ext_vector_type(4)));   // NT-builtin-compatible

__device__ __forceinline__ floatx4 nt_load4(const float* p) {
    return __builtin_nontemporal_load(reinterpret_cast<const floatx4*>(p));
}
__device__ __forceinline__ void nt_store4(float* p, floatx4 v) {
    __builtin_nontemporal_store(v, reinterpret_cast<floatx4*>(p));
}

// pack (uint8): bits0..3 label (argmax of one-hot 0..13) | bits4..7 ca_init
// CA state (uint16): bit0 empty | bit1 active | bits4..7 fca | bits8..11 src | bit12 overwritten

// ---------------- K1: per-pixel pack, pure streaming (14R NT, 1 tiny W) ----------------
__global__ __launch_bounds__(kThreads)
void k_pack(const float* __restrict__ world, const float* __restrict__ info,
            float* __restrict__ out, unsigned char* __restrict__ pack)
{
    const int g = blockIdx.x * kThreads + threadIdx.x;   // 524288 float4-groups
    const int b = g >> 14;                                // 16384 groups per plane
    const int rem = g & 16383;
    const size_t off = (size_t)rem << 2;
    const float* wb = world + (size_t)b * kNC * kPlane;

    int lab[4] = {0, 0, 0, 0};      // channel 0 implied: if no ch1..13 holds 1.0 -> label 0
    #pragma unroll
    for (int c = 1; c < kNE; ++c) {
        const floatx4 v = nt_load4(wb + (size_t)c * kPlane + off);
        if (v.x > 0.5f) lab[0] = c;      // exact one-hot: unique channel holds 1.0
        if (v.y > 0.5f) lab[1] = c;
        if (v.z > 0.5f) lab[2] = c;
        if (v.w > 0.5f) lab[3] = c;
    }
    const floatx4 ca4 = nt_load4(wb + (size_t)kCA * kPlane + off);
    uchar4 p;
    p.x = (unsigned char)(lab[0] | ((int)ca4.x << 4));
    p.y = (unsigned char)(lab[1] | ((int)ca4.y << 4));
    p.z = (unsigned char)(lab[2] | ((int)ca4.z << 4));
    p.w = (unsigned char)(lab[3] | ((int)ca4.w << 4));
    *reinterpret_cast<uchar4*>(pack + (size_t)b * kPlane + off) = p;   // re-read by K2: cached

    if (g < kB) out[(size_t)kB * kNC * kPlane + g] = info[g];   // info passthrough
}

// one mask-evolution step: self s, neighbor ns (both CA-state words)
__device__ __forceinline__ unsigned bc_step(unsigned s, unsigned ns,
                                            const unsigned short* __restrict__ vb) {
    if ((ns & 2u) && (s & 1u)) {
        const unsigned v = (ns >> 4) & 15u;
        return (s & 0x00F0u) | vb[v] | (v << 8) | 0x1000u;
    }
    return s;
}

// ---------------- K2: full-width stripe; select-in-register; NT writes ----------------
__global__ __launch_bounds__(kThreads)
void k_apply(const float* __restrict__ world, const float* __restrict__ ev,
             const unsigned char* __restrict__ pack, float* __restrict__ out)
{
    __shared__ unsigned char  sP[kSH + 4][kW];   // rows y0-2 .. y0+5 (wrapped)
    __shared__ unsigned short sA[kSH + 2][kW];   // CA state rows y0-1 .. y0+4
    __shared__ float sEV[kNE * kNC];
    __shared__ unsigned short sVbits[kNE];

    const int tid = threadIdx.x;
    const int y0 = blockIdx.x * kSH;
    const int b  = blockIdx.y;
    const float* wb = world + (size_t)b * kNC * kPlane;
    float*       ob = out   + (size_t)b * kNC * kPlane;
    const unsigned char* pb = pack + (size_t)b * kPlane;

    const int th   = tid >> 6;              // row in stripe (0..3); wave = 1 full row
    const int col4 = (tid & 63) * 4;
    const size_t off4 = (size_t)(y0 + th) * kW + col4;

    // Early-issue pass-through channel loads (single-touch -> NT; hide under LDS phases).
    floatx4 extra[5];
    extra[0] = nt_load4(wb + (size_t)14 * kPlane + off4);
    extra[1] = nt_load4(wb + (size_t)15 * kPlane + off4);
    extra[2] = nt_load4(wb + (size_t)16 * kPlane + off4);
    extra[3] = nt_load4(wb + (size_t)18 * kPlane + off4);
    extra[4] = nt_load4(wb + (size_t)19 * kPlane + off4);

    for (int i = tid; i < kNE * kNC; i += kThreads) sEV[i] = ev[i];
    if (tid < kNE) {
        const float e0  = ev[tid * kNC + 0];
        const float c13 = ev[tid * kNC + kCloner];
        const float c17 = ev[tid * kNC + kCA];
        unsigned short vb = 0;
        if (e0 > 0.5f) vb |= 1;                                     // empty after overwrite
        if (c13 > 0.5f && c17 != 0.0f && c17 != 13.0f) vb |= 2;     // active after overwrite
        sVbits[tid] = vb;
    }

    // pack rows y0-2..y0+5 (uchar4, contiguous per row; row wrap via &255)
    for (int idx = tid; idx < (kSH + 4) * (kW / 4); idx += kThreads) {
        const int r  = idx >> 6;            // 0..7
        const int c4 = (idx & 63) * 4;
        const int h  = (y0 - 2 + r) & (kH - 1);
        *reinterpret_cast<uchar4*>(&sP[r][c4]) =
            *reinterpret_cast<const uchar4*>(pb + (size_t)h * kW + c4);
    }
    __syncthreads();

    // phase A: final CA + state init on rows y0-1..y0+4 (sP rows 1..6), full width
    for (int idx = tid; idx < (kSH + 2) * kW; idx += kThreads) {
        const int r   = idx >> 8;           // 0..5 (sA row)
        const int col = idx & 255;
        const int pr  = r + 1;              // sP row
        const unsigned p  = sP[pr][col];
        const unsigned lb = p & 15u;
        int fca = 0;
        if (lb == kCloner) {                // cloner: sequentially absorb neighbor labels
            int ca = (int)(p >> 4);
            if (ca == 0 || ca == 13) ca = sP[pr + 1][col] & 15;            // below
            if (ca == 0 || ca == 13) ca = sP[pr - 1][col] & 15;            // above
            if (ca == 0 || ca == 13) ca = sP[pr][(col - 1) & 255] & 15;    // left
            if (ca == 0 || ca == 13) ca = sP[pr][(col + 1) & 255] & 15;    // right
            fca = ca;
        }
        unsigned short s = (unsigned short)(fca << 4);
        if (lb == 0) s |= 1;                                  // empty
        if (lb == kCloner && fca != 0 && fca != 13) s |= 2;   // active
        sA[r][col] = s;
    }
    __syncthreads();

    // phase B in registers: 4 direction steps over the 3x6 cone (column-wrapped)
    const int ar = th + 1;                  // sA row of the output row
    unsigned s0[3][6];
    #pragma unroll
    for (int r = 0; r < 3; ++r)
        #pragma unroll
        for (int c = 0; c < 6; ++c)
            s0[r][c] = sA[ar - 1 + r][(col4 - 1 + c) & 255];

    unsigned s1[2][6];
    #pragma unroll
    for (int r = 0; r < 2; ++r)
        #pragma unroll
        for (int c = 0; c < 6; ++c)
            s1[r][c] = bc_step(s0[r][c], s0[r + 1][c], sVbits);   // below

    unsigned s2[6];
    #pragma unroll
    for (int c = 0; c < 6; ++c)
        s2[c] = bc_step(s1[1][c], s1[0][c], sVbits);              // above

    unsigned s3[5];
    #pragma unroll
    for (int c = 0; c < 5; ++c)
        s3[c] = bc_step(s2[c + 1], s2[c], sVbits);                // left

    unsigned s4[4];
    #pragma unroll
    for (int j = 0; j < 4; ++j)
        s4[j] = bc_step(s3[j], s3[j + 1], sVbits);                // right

    bool  o[4]; int src[4]; float fcaf[4]; int lb[4];
    #pragma unroll
    for (int j = 0; j < 4; ++j) {
        o[j]    = (s4[j] & 0x1000u) != 0;
        src[j]  = (s4[j] >> 8) & 15;
        fcaf[j] = (float)((s4[j] >> 4) & 15);
        lb[j]   = sP[th + 2][col4 + j] & 15;
    }

    // Write all 20 channels in 5 groups of 4. Per group, load each pixel's
    // elem_vecs slice as ONE ds_read_b128 (sEV rows are 80B = 16B-aligned).
    // Select in registers, single NT store per channel (no WAW, no L2 dirty reuse).
    #pragma unroll
    for (int cg = 0; cg < 5; ++cg) {
        float evf[4][4];
        #pragma unroll
        for (int j = 0; j < 4; ++j) {
            const float4 t = *reinterpret_cast<const float4*>(&sEV[src[j] * kNC + 4 * cg]);
            evf[j][0] = t.x; evf[j][1] = t.y; evf[j][2] = t.z; evf[j][3] = t.w;
        }
        #pragma unroll
        for (int cc = 0; cc < 4; ++cc) {
            const int c = 4 * cg + cc;
            float base[4];
            if (c < kNE) {
                #pragma unroll
                for (int j = 0; j < 4; ++j) base[j] = (lb[j] == c) ? 1.0f : 0.0f;
            } else if (c == kCA) {
                #pragma unroll
                for (int j = 0; j < 4; ++j) base[j] = fcaf[j];
            } else {
                const floatx4 v = extra[c < kCA ? c - kNE : c - kNE - 1];
                base[0] = v.x; base[1] = v.y; base[2] = v.z; base[3] = v.w;
            }
            floatx4 r;
            r.x = o[0] ? evf[0][cc] : base[0];
            r.y = o[1] ? evf[1][cc] : base[1];
            r.z = o[2] ? evf[2][cc] : base[2];
            r.w = o[3] ? evf[3][cc] : base[3];
            nt_store4(ob + (size_t)c * kPlane + off4, r);
        }
    }
}

// ---------------- Fallback (round-3 fused kernel), used only if ws too small ----------
__global__ __launch_bounds__(kThreads)
void bc_fused(const float* __restrict__ world, const float* __restrict__ ev,
              const float* __restrict__ info, float* __restrict__ out)
{
    __shared__ unsigned short sPack[kE][kLW];
    __shared__ unsigned short sA[kE][kLW];
    __shared__ unsigned short sB[kE][kLW];
    __shared__ float sEV[kNE * kNC];
    __shared__ unsigned short sVbits[kNE];

    const int tid = threadIdx.x;
    const int b  = blockIdx.z;
    const int h0 = blockIdx.y * kT;
    const int w0 = blockIdx.x * kT;
    const float* wb = world + (size_t)b * kNC * kPlane;
    float*       ob = out   + (size_t)b * kNC * kPlane;

    for (int i = tid; i < kNE * kNC; i += kThreads) sEV[i] = ev[i];
    if (tid < kNE) {
        const float e0  = ev[tid * kNC + 0];
        const float c13 = ev[tid * kNC + kCloner];
        const float c17 = ev[tid * kNC + kCA];
        unsigned short vb = 0;
        if (e0 > 0.5f) vb |= 1;
        if (c13 > 0.5f && c17 != 0.0f && c17 != 13.0f) vb |= 2;
        sVbits[tid] = vb;
    }
    for (int idx = tid; idx < kE * 10; idx += kThreads) {
        const int eh = idx / 10;
        const int k  = idx - eh * 10;
        const int h = (h0 + eh - 2) & (kH - 1);
        const int w = (w0 - 4 + 4 * k) & (kW - 1);
        const size_t off = (size_t)h * kW + w;
        int lab[4] = {0,0,0,0};
        #pragma unroll
        for (int c = 0; c < kNE; ++c) {
            const float4 v = *reinterpret_cast<const float4*>(wb + (size_t)c * kPlane + off);
            if (v.x > 0.5f) lab[0] = c;
            if (v.y > 0.5f) lab[1] = c;
            if (v.z > 0.5f) lab[2] = c;
            if (v.w > 0.5f) lab[3] = c;
        }
        const float4 ca4 = *reinterpret_cast<const float4*>(wb + (size_t)kCA * kPlane + off);
        const int cai[4] = {(int)ca4.x, (int)ca4.y, (int)ca4.z, (int)ca4.w};
        #pragma unroll
        for (int j = 0; j < 4; ++j) {
            unsigned short p = (unsigned short)(lab[j] | (cai[j] << 8));
            if (lab[j] == kCloner) p |= 16;
            if (lab[j] == 0)       p |= 32;
            sPack[eh][4 * k + j] = p;
        }
    }
    __syncthreads();
    for (int idx = tid; idx < 34 * 34; idx += kThreads) {
        const int eh = idx / 34 + 1;
        const int lw = idx % 34 + 3;
        const unsigned short p = sPack[eh][lw];
        int fca = 0;
        if (p & 16) {
            int ca = (p >> 8) & 15;
            if (ca == 0 || ca == 13) ca = sPack[eh + 1][lw] & 15;
            if (ca == 0 || ca == 13) ca = sPack[eh - 1][lw] & 15;
            if (ca == 0 || ca == 13) ca = sPack[eh][lw - 1] & 15;
            if (ca == 0 || ca == 13) ca = sPack[eh][lw + 1] & 15;
            fca = ca;
        }
        unsigned short s = (unsigned short)(fca << 4);
        if (p & 32) s |= 1;
        if ((p & 16) && fca != 0 && fca != 13) s |= 2;
        sA[eh][lw] = s;
    }
    unsigned short (*prev)[kLW] = sA;
    unsigned short (*next)[kLW] = sB;
    {
        const int dh[4]   = {1, -1, 0, 0};
        const int dw[4]   = {0, 0, -1, 1};
        const int rhlo[4] = {1, 2, 2, 2};
        const int rhhi[4] = {33, 33, 33, 33};
        const int rwlo[4] = {3, 3, 4, 4};
        const int rwhi[4] = {36, 36, 36, 35};
        for (int d = 0; d < 4; ++d) {
            __syncthreads();
            const int nh = rhhi[d] - rhlo[d] + 1;
            const int nw = rwhi[d] - rwlo[d] + 1;
            for (int idx = tid; idx < nh * nw; idx += kThreads) {
                const int eh = rhlo[d] + idx / nw;
                const int lw = rwlo[d] + idx % nw;
                unsigned short s = prev[eh][lw];
                const unsigned short ns = prev[eh + dh[d]][lw + dw[d]];
                if ((ns & 2) && (s & 1)) {
                    const int v = (ns >> 4) & 15;
                    s = (unsigned short)((s & 0x00F0) | sVbits[v] | (v << 8) | 0x1000);
                }
                next[eh][lw] = s;
            }
            unsigned short (*t)[kLW] = prev; prev = next; next = t;
        }
    }
    __syncthreads();
    {
        const int th = tid >> 3;
        const int tw = (tid & 7) * 4;
        const int eh = th + 2;
        const size_t off = (size_t)(h0 + th) * kW + (w0 + tw);
        bool  o[4]; int src[4]; float fcaf[4]; int lb[4];
        #pragma unroll
        for (int j = 0; j < 4; ++j) {
            const unsigned short s = prev[eh][tw + 4 + j];
            o[j]    = (s & 0x1000) != 0;
            src[j]  = (s >> 8) & 15;
            fcaf[j] = (float)((s >> 4) & 15);
            lb[j]   = sPack[eh][tw + 4 + j] & 15;
        }
        #pragma unroll
        for (int c = 0; c < kNC; ++c) {
            float base[4];
            if (c >= kNE && c != kCA) {
                const float4 v = *reinterpret_cast<const float4*>(wb + (size_t)c * kPlane + off);
                base[0] = v.x; base[1] = v.y; base[2] = v.z; base[3] = v.w;
            } else if (c == kCA) {
                base[0] = fcaf[0]; base[1] = fcaf[1]; base[2] = fcaf[2]; base[3] = fcaf[3];
            } else {
                #pragma unroll
                for (int j = 0; j < 4; ++j) base[j] = (lb[j] == c) ? 1.0f : 0.0f;
            }
            float4 r;
            r.x = o[0] ? sEV[src[0] * kNC + c] : base[0];
            r.y = o[1] ? sEV[src[1] * kNC + c] : base[1];
            r.z = o[2] ? sEV[src[2] * kNC + c] : base[2];
            r.w = o[3] ? sEV[src[3] * kNC + c] : base[3];
            *reinterpret_cast<float4*>(ob + (size_t)c * kPlane + off) = r;
        }
    }
    if (blockIdx.x == 0 && blockIdx.y == 0 && blockIdx.z == 0 && tid < kB) {
        out[(size_t)kB * kNC * kPlane + tid] = info[tid];
    }
}

extern "C" void kernel_launch(void* const* d_in, const int* in_sizes, int n_in,
                              void* d_out, int out_size, void* d_ws, size_t ws_size,
                              hipStream_t stream) {
    const float* world = (const float*)d_in[0];
    const float* ev    = (const float*)d_in[1];
    const float* info  = (const float*)d_in[2];
    float* out = (float*)d_out;
    const size_t packBytes = (size_t)kB * kPlane;   // 2.1 MB (uint8)
    if (ws_size >= packBytes) {
        unsigned char* pack = (unsigned char*)d_ws;
        k_pack<<<dim3((kB * (int)kPlane / 4) / kThreads), kThreads, 0, stream>>>(world, info, out, pack);
        k_apply<<<dim3(kH / kSH, kB), kThreads, 0, stream>>>(world, ev, pack, out);
    } else {
        bc_fused<<<dim3(kW / kT, kH / kT, kB), kThreads, 0, stream>>>(world, ev, info, out);
    }
}

// Round 12
// 64.912 us; speedup vs baseline: 1.6004x; 1.0013x over previous
//
#include <hip/hip_runtime.h>

namespace {
constexpr int kNE = 14;
constexpr int kNC = 20;
constexpr int kCloner = 13;
constexpr int kCA = 17;   // NE + 3
constexpr int kB = 32;
constexpr int kH = 256;
constexpr int kW = 256;

constexpr int kSH = 4;        // stripe height (full width)
constexpr int kThreads = 256;
constexpr size_t kPlane = (size_t)kH * kW;

// fallback tile geometry (round-3 kernel)
constexpr int kT = 32;
constexpr int kE = kT + 4;
constexpr int kLW = 40;
}

typedef float floatx4 __attribute__((ext_vector_type(4)));   // NT-builtin-compatible

__device__ __forceinline__ floatx4 nt_load4(const float* p) {
    return __builtin_nontemporal_load(reinterpret_cast<const floatx4*>(p));
}
__device__ __forceinline__ void nt_store4(float* p, floatx4 v) {
    __builtin_nontemporal_store(v, reinterpret_cast<floatx4*>(p));
}

// pack (uint8): bits0..3 label (argmax of one-hot 0..13) | bits4..7 ca_init
// CA state (uint16): bit0 empty | bit1 active | bits4..7 fca | bits8..11 src | bit12 overwritten

// ---------------- K1: per-pixel pack, pure streaming (14R NT, 1 tiny W) ----------------
__global__ __launch_bounds__(kThreads)
void k_pack(const float* __restrict__ world, const float* __restrict__ info,
            float* __restrict__ out, unsigned char* __restrict__ pack)
{
    const int g = blockIdx.x * kThreads + threadIdx.x;   // 524288 float4-groups
    const int b = g >> 14;                                // 16384 groups per plane
    const int rem = g & 16383;
    const size_t off = (size_t)rem << 2;
    const float* wb = world + (size_t)b * kNC * kPlane;

    int lab[4] = {0, 0, 0, 0};      // channel 0 implied: if no ch1..13 holds 1.0 -> label 0
    #pragma unroll
    for (int c = 1; c < kNE; ++c) {
        const floatx4 v = nt_load4(wb + (size_t)c * kPlane + off);
        if (v.x > 0.5f) lab[0] = c;      // exact one-hot: unique channel holds 1.0
        if (v.y > 0.5f) lab[1] = c;
        if (v.z > 0.5f) lab[2] = c;
        if (v.w > 0.5f) lab[3] = c;
    }
    const floatx4 ca4 = nt_load4(wb + (size_t)kCA * kPlane + off);
    uchar4 p;
    p.x = (unsigned char)(lab[0] | ((int)ca4.x << 4));
    p.y = (unsigned char)(lab[1] | ((int)ca4.y << 4));
    p.z = (unsigned char)(lab[2] | ((int)ca4.z << 4));
    p.w = (unsigned char)(lab[3] | ((int)ca4.w << 4));
    *reinterpret_cast<uchar4*>(pack + (size_t)b * kPlane + off) = p;   // re-read by K2: cached

    if (g < kB) out[(size_t)kB * kNC * kPlane + g] = info[g];   // info passthrough
}

// one mask-evolution step: self s, neighbor ns (both CA-state words)
__device__ __forceinline__ unsigned bc_step(unsigned s, unsigned ns,
                                            const unsigned short* __restrict__ vb) {
    if ((ns & 2u) && (s & 1u)) {
        const unsigned v = (ns >> 4) & 15u;
        return (s & 0x00F0u) | vb[v] | (v << 8) | 0x1000u;
    }
    return s;
}

// ---------------- K2<CGLO,CGHI>: stripe CA sim + write channel groups [CGLO,CGHI) ------
// Channel group cg covers channels 4cg..4cg+3. <0,3> = ch0-11 (one-hot only, pure-write);
// <3,5> = ch12-19 (one-hot 12,13; extra 14,15,16,18,19; ca 17).
template <int CGLO, int CGHI>
__global__ __launch_bounds__(kThreads)
void k_apply(const float* __restrict__ world, const float* __restrict__ ev,
             const unsigned char* __restrict__ pack, float* __restrict__ out)
{
    __shared__ unsigned char  sP[kSH + 4][kW];   // rows y0-2 .. y0+5 (wrapped)
    __shared__ unsigned short sA[kSH + 2][kW];   // CA state rows y0-1 .. y0+4
    __shared__ float sEV[kNE * kNC];
    __shared__ unsigned short sVbits[kNE];

    const int tid = threadIdx.x;
    const int y0 = blockIdx.x * kSH;
    const int b  = blockIdx.y;
    const float* wb = world + (size_t)b * kNC * kPlane;
    float*       ob = out   + (size_t)b * kNC * kPlane;
    const unsigned char* pb = pack + (size_t)b * kPlane;

    const int th   = tid >> 6;              // row in stripe (0..3); wave = 1 full row
    const int col4 = (tid & 63) * 4;
    const size_t off4 = (size_t)(y0 + th) * kW + col4;

    // Early-issue pass-through channel loads (single-touch -> NT; hide under LDS phases).
    floatx4 extra[5];
    if (CGHI > 3) {
        extra[0] = nt_load4(wb + (size_t)14 * kPlane + off4);
        extra[1] = nt_load4(wb + (size_t)15 * kPlane + off4);
        extra[2] = nt_load4(wb + (size_t)16 * kPlane + off4);
        extra[3] = nt_load4(wb + (size_t)18 * kPlane + off4);
        extra[4] = nt_load4(wb + (size_t)19 * kPlane + off4);
    }

    for (int i = tid; i < kNE * kNC; i += kThreads) sEV[i] = ev[i];
    if (tid < kNE) {
        const float e0  = ev[tid * kNC + 0];
        const float c13 = ev[tid * kNC + kCloner];
        const float c17 = ev[tid * kNC + kCA];
        unsigned short vb = 0;
        if (e0 > 0.5f) vb |= 1;                                     // empty after overwrite
        if (c13 > 0.5f && c17 != 0.0f && c17 != 13.0f) vb |= 2;     // active after overwrite
        sVbits[tid] = vb;
    }

    // pack rows y0-2..y0+5 (uchar4, contiguous per row; row wrap via &255)
    for (int idx = tid; idx < (kSH + 4) * (kW / 4); idx += kThreads) {
        const int r  = idx >> 6;            // 0..7
        const int c4 = (idx & 63) * 4;
        const int h  = (y0 - 2 + r) & (kH - 1);
        *reinterpret_cast<uchar4*>(&sP[r][c4]) =
            *reinterpret_cast<const uchar4*>(pb + (size_t)h * kW + c4);
    }
    __syncthreads();

    // phase A: final CA + state init on rows y0-1..y0+4 (sP rows 1..6), full width
    for (int idx = tid; idx < (kSH + 2) * kW; idx += kThreads) {
        const int r   = idx >> 8;           // 0..5 (sA row)
        const int col = idx & 255;
        const int pr  = r + 1;              // sP row
        const unsigned p  = sP[pr][col];
        const unsigned lb = p & 15u;
        int fca = 0;
        if (lb == kCloner) {                // cloner: sequentially absorb neighbor labels
            int ca = (int)(p >> 4);
            if (ca == 0 || ca == 13) ca = sP[pr + 1][col] & 15;            // below
            if (ca == 0 || ca == 13) ca = sP[pr - 1][col] & 15;            // above
            if (ca == 0 || ca == 13) ca = sP[pr][(col - 1) & 255] & 15;    // left
            if (ca == 0 || ca == 13) ca = sP[pr][(col + 1) & 255] & 15;    // right
            fca = ca;
        }
        unsigned short s = (unsigned short)(fca << 4);
        if (lb == 0) s |= 1;                                  // empty
        if (lb == kCloner && fca != 0 && fca != 13) s |= 2;   // active
        sA[r][col] = s;
    }
    __syncthreads();

    // phase B in registers: 4 direction steps over the 3x6 cone (column-wrapped)
    const int ar = th + 1;                  // sA row of the output row
    unsigned s0[3][6];
    #pragma unroll
    for (int r = 0; r < 3; ++r)
        #pragma unroll
        for (int c = 0; c < 6; ++c)
            s0[r][c] = sA[ar - 1 + r][(col4 - 1 + c) & 255];

    unsigned s1[2][6];
    #pragma unroll
    for (int r = 0; r < 2; ++r)
        #pragma unroll
        for (int c = 0; c < 6; ++c)
            s1[r][c] = bc_step(s0[r][c], s0[r + 1][c], sVbits);   // below

    unsigned s2[6];
    #pragma unroll
    for (int c = 0; c < 6; ++c)
        s2[c] = bc_step(s1[1][c], s1[0][c], sVbits);              // above

    unsigned s3[5];
    #pragma unroll
    for (int c = 0; c < 5; ++c)
        s3[c] = bc_step(s2[c + 1], s2[c], sVbits);                // left

    unsigned s4[4];
    #pragma unroll
    for (int j = 0; j < 4; ++j)
        s4[j] = bc_step(s3[j], s3[j + 1], sVbits);                // right

    bool  o[4]; int src[4]; float fcaf[4]; int lb[4];
    #pragma unroll
    for (int j = 0; j < 4; ++j) {
        o[j]    = (s4[j] & 0x1000u) != 0;
        src[j]  = (s4[j] >> 8) & 15;
        fcaf[j] = (float)((s4[j] >> 4) & 15);
        lb[j]   = sP[th + 2][col4 + j] & 15;
    }

    // Write channel groups [CGLO,CGHI). Per group, each pixel's elem_vecs slice is
    // ONE ds_read_b128 (sEV rows 80B, 16B-aligned). Select in registers, single NT store.
    #pragma unroll
    for (int cg = CGLO; cg < CGHI; ++cg) {
        float evf[4][4];
        #pragma unroll
        for (int j = 0; j < 4; ++j) {
            const float4 t = *reinterpret_cast<const float4*>(&sEV[src[j] * kNC + 4 * cg]);
            evf[j][0] = t.x; evf[j][1] = t.y; evf[j][2] = t.z; evf[j][3] = t.w;
        }
        #pragma unroll
        for (int cc = 0; cc < 4; ++cc) {
            const int c = 4 * cg + cc;
            float base[4];
            if (c < kNE) {
                #pragma unroll
                for (int j = 0; j < 4; ++j) base[j] = (lb[j] == c) ? 1.0f : 0.0f;
            } else if (c == kCA) {
                #pragma unroll
                for (int j = 0; j < 4; ++j) base[j] = fcaf[j];
            } else {
                const floatx4 v = extra[c < kCA ? c - kNE : c - kNE - 1];
                base[0] = v.x; base[1] = v.y; base[2] = v.z; base[3] = v.w;
            }
            floatx4 r;
            r.x = o[0] ? evf[0][cc] : base[0];
            r.y = o[1] ? evf[1][cc] : base[1];
            r.z = o[2] ? evf[2][cc] : base[2];
            r.w = o[3] ? evf[3][cc] : base[3];
            nt_store4(ob + (size_t)c * kPlane + off4, r);
        }
    }
}

// ---------------- Fallback (round-3 fused kernel), used only if ws too small ----------
__global__ __launch_bounds__(kThreads)
void bc_fused(const float* __restrict__ world, const float* __restrict__ ev,
              const float* __restrict__ info, float* __restrict__ out)
{
    __shared__ unsigned short sPack[kE][kLW];
    __shared__ unsigned short sA[kE][kLW];
    __shared__ unsigned short sB[kE][kLW];
    __shared__ float sEV[kNE * kNC];
    __shared__ unsigned short sVbits[kNE];

    const int tid = threadIdx.x;
    const int b  = blockIdx.z;
    const int h0 = blockIdx.y * kT;
    const int w0 = blockIdx.x * kT;
    const float* wb = world + (size_t)b * kNC * kPlane;
    float*       ob = out   + (size_t)b * kNC * kPlane;

    for (int i = tid; i < kNE * kNC; i += kThreads) sEV[i] = ev[i];
    if (tid < kNE) {
        const float e0  = ev[tid * kNC + 0];
        const float c13 = ev[tid * kNC + kCloner];
        const float c17 = ev[tid * kNC + kCA];
        unsigned short vb = 0;
        if (e0 > 0.5f) vb |= 1;
        if (c13 > 0.5f && c17 != 0.0f && c17 != 13.0f) vb |= 2;
        sVbits[tid] = vb;
    }
    for (int idx = tid; idx < kE * 10; idx += kThreads) {
        const int eh = idx / 10;
        const int k  = idx - eh * 10;
        const int h = (h0 + eh - 2) & (kH - 1);
        const int w = (w0 - 4 + 4 * k) & (kW - 1);
        const size_t off = (size_t)h * kW + w;
        int lab[4] = {0,0,0,0};
        #pragma unroll
        for (int c = 0; c < kNE; ++c) {
            const float4 v = *reinterpret_cast<const float4*>(wb + (size_t)c * kPlane + off);
            if (v.x > 0.5f) lab[0] = c;
            if (v.y > 0.5f) lab[1] = c;
            if (v.z > 0.5f) lab[2] = c;
            if (v.w > 0.5f) lab[3] = c;
        }
        const float4 ca4 = *reinterpret_cast<const float4*>(wb + (size_t)kCA * kPlane + off);
        const int cai[4] = {(int)ca4.x, (int)ca4.y, (int)ca4.z, (int)ca4.w};
        #pragma unroll
        for (int j = 0; j < 4; ++j) {
            unsigned short p = (unsigned short)(lab[j] | (cai[j] << 8));
            if (lab[j] == kCloner) p |= 16;
            if (lab[j] == 0)       p |= 32;
            sPack[eh][4 * k + j] = p;
        }
    }
    __syncthreads();
    for (int idx = tid; idx < 34 * 34; idx += kThreads) {
        const int eh = idx / 34 + 1;
        const int lw = idx % 34 + 3;
        const unsigned short p = sPack[eh][lw];
        int fca = 0;
        if (p & 16) {
            int ca = (p >> 8) & 15;
            if (ca == 0 || ca == 13) ca = sPack[eh + 1][lw] & 15;
            if (ca == 0 || ca == 13) ca = sPack[eh - 1][lw] & 15;
            if (ca == 0 || ca == 13) ca = sPack[eh][lw - 1] & 15;
            if (ca == 0 || ca == 13) ca = sPack[eh][lw + 1] & 15;
            fca = ca;
        }
        unsigned short s = (unsigned short)(fca << 4);
        if (p & 32) s |= 1;
        if ((p & 16) && fca != 0 && fca != 13) s |= 2;
        sA[eh][lw] = s;
    }
    unsigned short (*prev)[kLW] = sA;
    unsigned short (*next)[kLW] = sB;
    {
        const int dh[4]   = {1, -1, 0, 0};
        const int dw[4]   = {0, 0, -1, 1};
        const int rhlo[4] = {1, 2, 2, 2};
        const int rhhi[4] = {33, 33, 33, 33};
        const int rwlo[4] = {3, 3, 4, 4};
        const int rwhi[4] = {36, 36, 36, 35};
        for (int d = 0; d < 4; ++d) {
            __syncthreads();
            const int nh = rhhi[d] - rhlo[d] + 1;
            const int nw = rwhi[d] - rwlo[d] + 1;
            for (int idx = tid; idx < nh * nw; idx += kThreads) {
                const int eh = rhlo[d] + idx / nw;
                const int lw = rwlo[d] + idx % nw;
                unsigned short s = prev[eh][lw];
                const unsigned short ns = prev[eh + dh[d]][lw + dw[d]];
                if ((ns & 2) && (s & 1)) {
                    const int v = (ns >> 4) & 15;
                    s = (unsigned short)((s & 0x00F0) | sVbits[v] | (v << 8) | 0x1000);
                }
                next[eh][lw] = s;
            }
            unsigned short (*t)[kLW] = prev; prev = next; next = t;
        }
    }
    __syncthreads();
    {
        const int th = tid >> 3;
        const int tw = (tid & 7) * 4;
        const int eh = th + 2;
        const size_t off = (size_t)(h0 + th) * kW + (w0 + tw);
        bool  o[4]; int src[4]; float fcaf[4]; int lb[4];
        #pragma unroll
        for (int j = 0; j < 4; ++j) {
            const unsigned short s = prev[eh][tw + 4 + j];
            o[j]    = (s & 0x1000) != 0;
            src[j]  = (s >> 8) & 15;
            fcaf[j] = (float)((s >> 4) & 15);
            lb[j]   = sPack[eh][tw + 4 + j] & 15;
        }
        #pragma unroll
        for (int c = 0; c < kNC; ++c) {
            float base[4];
            if (c >= kNE && c != kCA) {
                const float4 v = *reinterpret_cast<const float4*>(wb + (size_t)c * kPlane + off);
                base[0] = v.x; base[1] = v.y; base[2] = v.z; base[3] = v.w;
            } else if (c == kCA) {
                base[0] = fcaf[0]; base[1] = fcaf[1]; base[2] = fcaf[2]; base[3] = fcaf[3];
            } else {
                #pragma unroll
                for (int j = 0; j < 4; ++j) base[j] = (lb[j] == c) ? 1.0f : 0.0f;
            }
            float4 r;
            r.x = o[0] ? sEV[src[0] * kNC + c] : base[0];
            r.y = o[1] ? sEV[src[1] * kNC + c] : base[1];
            r.z = o[2] ? sEV[src[2] * kNC + c] : base[2];
            r.w = o[3] ? sEV[src[3] * kNC + c] : base[3];
            *reinterpret_cast<float4*>(ob + (size_t)c * kPlane + off) = r;
        }
    }
    if (blockIdx.x == 0 && blockIdx.y == 0 && blockIdx.z == 0 && tid < kB) {
        out[(size_t)kB * kNC * kPlane + tid] = info[tid];
    }
}

extern "C" void kernel_launch(void* const* d_in, const int* in_sizes, int n_in,
                              void* d_out, int out_size, void* d_ws, size_t ws_size,
                              hipStream_t stream) {
    const float* world = (const float*)d_in[0];
    const float* ev    = (const float*)d_in[1];
    const float* info  = (const float*)d_in[2];
    float* out = (float*)d_out;
    const size_t packBytes = (size_t)kB * kPlane;   // 2.1 MB (uint8)
    if (ws_size >= packBytes) {
        unsigned char* pack = (unsigned char*)d_ws;
        k_pack<<<dim3((kB * (int)kPlane / 4) / kThreads), kThreads, 0, stream>>>(world, info, out, pack);
        k_apply<0, 3><<<dim3(kH / kSH, kB), kThreads, 0, stream>>>(world, ev, pack, out);  // ch0-11
        k_apply<3, 5><<<dim3(kH / kSH, kB), kThreads, 0, stream>>>(world, ev, pack, out);  // ch12-19
    } else {
        bc_fused<<<dim3(kW / kT, kH / kT, kB), kThreads, 0, stream>>>(world, ev, info, out);
    }
}